// Round 17
// baseline (318.924 us; speedup 1.0000x reference)
//
#include <hip/hip_runtime.h>
#include <hip/hip_bf16.h>

#define HDIM 128
#define BM 64
#define KB 16

typedef __bf16 bf16x8 __attribute__((ext_vector_type(8)));
typedef float f32x4 __attribute__((ext_vector_type(4)));

union Frag {
  bf16x8 v;
  uint4 u4;
  ushort u[8];
};

// ---------------------------------------------------------------------------
// Tiled fp32 GEMM (R13-proven) for layer 0; optionally zeroes zbuf first.
// ---------------------------------------------------------------------------
__global__ __launch_bounds__(256) void gemm_tiled(
    const float* __restrict__ A, const float* __restrict__ W,
    const float* __restrict__ bias, float* __restrict__ outf, int n,
    int* __restrict__ zbuf, int zn) {
  if (zbuf) {
    for (int i = blockIdx.x * 256 + threadIdx.x; i < zn; i += gridDim.x * 256)
      zbuf[i] = 0;
  }
  __shared__ float sA[KB][BM];
  __shared__ float sW[KB][HDIM];
  const int tid = threadIdx.x;
  const int tx = tid & 15;
  const int ty = tid >> 4;
  const int block_row = blockIdx.x * BM;

  float acc[4][8];
#pragma unroll
  for (int i = 0; i < 4; ++i)
#pragma unroll
    for (int j = 0; j < 8; ++j) acc[i][j] = 0.f;

  const int ar = tid >> 2;
  const int ak = (tid & 3) << 2;
  const int wk = tid >> 4;
  const int wc = (tid & 15) << 3;

  for (int k0 = 0; k0 < HDIM; k0 += KB) {
    float4 av = make_float4(0.f, 0.f, 0.f, 0.f);
    int grow = block_row + ar;
    if (grow < n) av = *(const float4*)(A + (size_t)grow * HDIM + k0 + ak);
    sA[ak + 0][ar] = av.x; sA[ak + 1][ar] = av.y;
    sA[ak + 2][ar] = av.z; sA[ak + 3][ar] = av.w;

    float4 w0 = *(const float4*)(W + (size_t)(k0 + wk) * HDIM + wc);
    float4 w1 = *(const float4*)(W + (size_t)(k0 + wk) * HDIM + wc + 4);
    *(float4*)&sW[wk][wc] = w0;
    *(float4*)&sW[wk][wc + 4] = w1;
    __syncthreads();

#pragma unroll
    for (int k = 0; k < KB; ++k) {
      float4 a = *(const float4*)&sA[k][ty * 4];
      float4 wA = *(const float4*)&sW[k][tx * 8];
      float4 wB = *(const float4*)&sW[k][tx * 8 + 4];
      float av4[4] = {a.x, a.y, a.z, a.w};
      float wv[8] = {wA.x, wA.y, wA.z, wA.w, wB.x, wB.y, wB.z, wB.w};
#pragma unroll
      for (int i = 0; i < 4; ++i)
#pragma unroll
        for (int j = 0; j < 8; ++j) acc[i][j] += av4[i] * wv[j];
    }
    __syncthreads();
  }

  float bj[8];
#pragma unroll
  for (int j = 0; j < 8; ++j) bj[j] = bias ? bias[tx * 8 + j] : 0.f;
#pragma unroll
  for (int i = 0; i < 4; ++i) {
    int grow = block_row + ty * 4 + i;
    if (grow < n) {
      float o[8];
#pragma unroll
      for (int j = 0; j < 8; ++j) o[j] = acc[i][j] + bj[j];
      *(float4*)(outf + (size_t)grow * HDIM + tx * 8) = *(float4*)&o[0];
      *(float4*)(outf + (size_t)grow * HDIM + tx * 8 + 4) = *(float4*)&o[4];
    }
  }
}

// ---------------------------------------------------------------------------
// prep_w2: split w1,w2 fp32 [k][c] into transposed bf16 hi/lo Wt[c][k].
// dst layout: [m][hi|lo][16384], m in {0,1}. Grid 128 blocks.
// ---------------------------------------------------------------------------
__global__ __launch_bounds__(256) void prep_w2(const float* __restrict__ w1s,
                                               const float* __restrict__ w2s,
                                               ushort* __restrict__ dst) {
  int m = blockIdx.x >> 6;
  int i = ((blockIdx.x & 63) << 8) + threadIdx.x;  // i = c*128 + k
  const float* W = (m == 0) ? w1s : w2s;
  int c = i >> 7, k = i & 127;
  float w = W[(size_t)k * HDIM + c];
  ushort h = __bfloat16_as_ushort(__float2bfloat16(w));
  float rem = w - __uint_as_float((uint32_t)h << 16);
  ushort* hi = dst + (size_t)m * 2 * HDIM * HDIM;
  hi[i] = h;
  hi[HDIM * HDIM + i] = __bfloat16_as_ushort(__float2bfloat16(rem));
}

// ---------------------------------------------------------------------------
// gemm_mfma2: out_bf16[n,128] = A[n,128] @ W, split-bf16 MFMA, attempt #3.
// R14/R15 failed because acc was loop-local (one tile at a time) -> compiler
// register-minimized (VGPR=36) and serialized the chains. Fix: kb-OUTER,
// tile-INNER with acc[8] live across the whole K loop -> 32 acc VGPRs are
// semantically forced, 8 independent MFMA chains, 16 W-loads batched per kb.
// Per-tile math identical to R14/R15 (absmax-verified fp32-equivalent).
// MFMA 16x16x32_bf16: A lane=m+16*(k/8),elem=k%8; B lane=n+16*(k/8);
// D col=lane&15, row=(lane>>4)*4+reg.
// ---------------------------------------------------------------------------
__global__ __launch_bounds__(256) void gemm_mfma2(
    const float* __restrict__ A, const ushort* __restrict__ Whi,
    const ushort* __restrict__ Wlo, __hip_bfloat16* __restrict__ outb, int n) {
  const int wave = threadIdx.x >> 6;
  const int lane = threadIdx.x & 63;
  const int l15 = lane & 15;
  const int kgrp = lane >> 4;                 // 0..3
  const int row0 = blockIdx.x * 64 + wave * 16;

  // A hi/lo fragments for this wave's 16 rows, all 4 K-blocks (32 VGPR).
  int r = row0 + l15;
  bool rok = r < n;
  const float* arow = A + (size_t)(rok ? r : 0) * HDIM;
  Frag ah[4], al[4];
#pragma unroll
  for (int kb = 0; kb < 4; ++kb) {
    int k0 = kb * 32 + kgrp * 8;
    float4 v0 = *(const float4*)(arow + k0);
    float4 v1 = *(const float4*)(arow + k0 + 4);
    float vv[8] = {v0.x, v0.y, v0.z, v0.w, v1.x, v1.y, v1.z, v1.w};
#pragma unroll
    for (int j = 0; j < 8; ++j) {
      float f = rok ? vv[j] : 0.f;
      ushort h = __bfloat16_as_ushort(__float2bfloat16(f));
      float rem = f - __uint_as_float((uint32_t)h << 16);
      ah[kb].u[j] = h;
      al[kb].u[j] = __bfloat16_as_ushort(__float2bfloat16(rem));
    }
  }

  // 8 accumulators, all live across the K loop (forced ILP-8).
  f32x4 acc[8];
#pragma unroll
  for (int t = 0; t < 8; ++t) acc[t] = (f32x4){0.f, 0.f, 0.f, 0.f};

#pragma unroll
  for (int kb = 0; kb < 4; ++kb) {
    int k0 = kb * 32 + kgrp * 8;
    // Batch-issue all 16 W fragment loads for this kb (MLP).
    Frag bh[8], bl[8];
#pragma unroll
    for (int t = 0; t < 8; ++t) {
      int c = t * 16 + l15;
      bh[t].u4 = *(const uint4*)(Whi + (size_t)c * HDIM + k0);
      bl[t].u4 = *(const uint4*)(Wlo + (size_t)c * HDIM + k0);
    }
    // 8 independent 3-MFMA chains.
#pragma unroll
    for (int t = 0; t < 8; ++t) {
      acc[t] = __builtin_amdgcn_mfma_f32_16x16x32_bf16(ah[kb].v, bh[t].v,
                                                       acc[t], 0, 0, 0);
      acc[t] = __builtin_amdgcn_mfma_f32_16x16x32_bf16(al[kb].v, bh[t].v,
                                                       acc[t], 0, 0, 0);
      acc[t] = __builtin_amdgcn_mfma_f32_16x16x32_bf16(ah[kb].v, bl[t].v,
                                                       acc[t], 0, 0, 0);
    }
  }

#pragma unroll
  for (int t = 0; t < 8; ++t) {
    int c = t * 16 + l15;
#pragma unroll
    for (int rg = 0; rg < 4; ++rg) {
      int rr = row0 + kgrp * 4 + rg;
      if (rr < n) outb[(size_t)rr * HDIM + c] = __float2bfloat16(acc[t][rg]);
    }
  }
}

// ---------------------------------------------------------------------------
// CSR build: hist -> scan1 -> scan3f -> fill (R16-measured).
// ---------------------------------------------------------------------------
__global__ __launch_bounds__(256) void hist_dst(const int* __restrict__ ei,
                                                int E, int n,
                                                int* __restrict__ deg) {
  int e = blockIdx.x * 256 + threadIdx.x;
  if (e < E) {
    int s = ei[e];
    int d = ei[E + e];
    if ((unsigned)s < (unsigned)n && (unsigned)d < (unsigned)n)
      atomicAdd(&deg[d], 1);
  }
}

__global__ __launch_bounds__(1024) void scan1(const int* __restrict__ deg,
                                              int* __restrict__ partials, int n) {
  __shared__ int sm[1024];
  int i = blockIdx.x * 1024 + threadIdx.x;
  sm[threadIdx.x] = (i < n) ? deg[i] : 0;
  __syncthreads();
  for (int d = 512; d > 0; d >>= 1) {
    if (threadIdx.x < d) sm[threadIdx.x] += sm[threadIdx.x + d];
    __syncthreads();
  }
  if (threadIdx.x == 0) partials[blockIdx.x] = sm[0];
}

__global__ __launch_bounds__(1024) void scan3f(const int* __restrict__ deg,
                                               const int* __restrict__ partials,
                                               int* __restrict__ off,
                                               int* __restrict__ cur, int n) {
  __shared__ int sm[1024];
  int tid = threadIdx.x;
  int pre = 0;
  for (int i = tid; i < blockIdx.x; i += 1024) pre += partials[i];
  sm[tid] = pre;
  __syncthreads();
  for (int d = 512; d > 0; d >>= 1) {
    if (tid < d) sm[tid] += sm[tid + d];
    __syncthreads();
  }
  int P = sm[0];
  __syncthreads();
  int i = blockIdx.x * 1024 + tid;
  int v = (i < n) ? deg[i] : 0;
  sm[tid] = v;
  __syncthreads();
  for (int d = 1; d < 1024; d <<= 1) {
    int t = (tid >= d) ? sm[tid - d] : 0;
    __syncthreads();
    sm[tid] += t;
    __syncthreads();
  }
  if (i < n) {
    int ex = P + sm[tid] - v;
    off[i] = ex;
    cur[i] = ex;
    if (i == n - 1) off[n] = ex + v;
  }
}

__global__ __launch_bounds__(256) void fill_csr(const int* __restrict__ ei,
                                                int E, int n,
                                                int* __restrict__ cur,
                                                int* __restrict__ csr) {
  int e = blockIdx.x * 256 + threadIdx.x;
  if (e < E) {
    int s = ei[e];
    int d = ei[E + e];
    if ((unsigned)d < (unsigned)n && (unsigned)s < (unsigned)n) {
      int slot = atomicAdd(&cur[d], 1);
      csr[slot] = s;
    }
  }
}

// ---------------------------------------------------------------------------
// Gather core (R13-measured): SGPR-pinned csr walk, 8-wide named-reg batches.
// ---------------------------------------------------------------------------
__device__ inline float2 bf2_unpack(uint32_t u) {
  float lo = __uint_as_float(u << 16);
  float hi = __uint_as_float(u & 0xffff0000u);
  return make_float2(lo, hi);
}

__device__ inline float2 gather_sum(const uint32_t* __restrict__ Mw,
                                    const int* __restrict__ off,
                                    const int* __restrict__ csr,
                                    int node, int lane) {
  float2 acc = bf2_unpack(Mw[(size_t)node * (HDIM / 2) + lane]);  // self loop
  int s = __builtin_amdgcn_readfirstlane(off[node]);
  int e = __builtin_amdgcn_readfirstlane(off[node + 1]);
  int j = s;
  for (; j + 8 <= e; j += 8) {
    int s0 = __builtin_amdgcn_readfirstlane(csr[j + 0]);
    int s1 = __builtin_amdgcn_readfirstlane(csr[j + 1]);
    int s2 = __builtin_amdgcn_readfirstlane(csr[j + 2]);
    int s3 = __builtin_amdgcn_readfirstlane(csr[j + 3]);
    int s4 = __builtin_amdgcn_readfirstlane(csr[j + 4]);
    int s5 = __builtin_amdgcn_readfirstlane(csr[j + 5]);
    int s6 = __builtin_amdgcn_readfirstlane(csr[j + 6]);
    int s7 = __builtin_amdgcn_readfirstlane(csr[j + 7]);
    uint32_t r0 = Mw[(size_t)s0 * (HDIM / 2) + lane];
    uint32_t r1 = Mw[(size_t)s1 * (HDIM / 2) + lane];
    uint32_t r2 = Mw[(size_t)s2 * (HDIM / 2) + lane];
    uint32_t r3 = Mw[(size_t)s3 * (HDIM / 2) + lane];
    uint32_t r4 = Mw[(size_t)s4 * (HDIM / 2) + lane];
    uint32_t r5 = Mw[(size_t)s5 * (HDIM / 2) + lane];
    uint32_t r6 = Mw[(size_t)s6 * (HDIM / 2) + lane];
    uint32_t r7 = Mw[(size_t)s7 * (HDIM / 2) + lane];
    float2 v0 = bf2_unpack(r0), v1 = bf2_unpack(r1);
    float2 v2 = bf2_unpack(r2), v3 = bf2_unpack(r3);
    float2 v4 = bf2_unpack(r4), v5 = bf2_unpack(r5);
    float2 v6 = bf2_unpack(r6), v7 = bf2_unpack(r7);
    acc.x += v0.x; acc.y += v0.y;
    acc.x += v1.x; acc.y += v1.y;
    acc.x += v2.x; acc.y += v2.y;
    acc.x += v3.x; acc.y += v3.y;
    acc.x += v4.x; acc.y += v4.y;
    acc.x += v5.x; acc.y += v5.y;
    acc.x += v6.x; acc.y += v6.y;
    acc.x += v7.x; acc.y += v7.y;
  }
  for (; j + 4 <= e; j += 4) {
    int s0 = __builtin_amdgcn_readfirstlane(csr[j + 0]);
    int s1 = __builtin_amdgcn_readfirstlane(csr[j + 1]);
    int s2 = __builtin_amdgcn_readfirstlane(csr[j + 2]);
    int s3 = __builtin_amdgcn_readfirstlane(csr[j + 3]);
    uint32_t r0 = Mw[(size_t)s0 * (HDIM / 2) + lane];
    uint32_t r1 = Mw[(size_t)s1 * (HDIM / 2) + lane];
    uint32_t r2 = Mw[(size_t)s2 * (HDIM / 2) + lane];
    uint32_t r3 = Mw[(size_t)s3 * (HDIM / 2) + lane];
    float2 v0 = bf2_unpack(r0), v1 = bf2_unpack(r1);
    float2 v2 = bf2_unpack(r2), v3 = bf2_unpack(r3);
    acc.x += v0.x; acc.y += v0.y;
    acc.x += v1.x; acc.y += v1.y;
    acc.x += v2.x; acc.y += v2.y;
    acc.x += v3.x; acc.y += v3.y;
  }
  for (; j < e; ++j) {
    int s0 = __builtin_amdgcn_readfirstlane(csr[j]);
    float2 v0 = bf2_unpack(Mw[(size_t)s0 * (HDIM / 2) + lane]);
    acc.x += v0.x; acc.y += v0.y;
  }
  return acc;
}

// agg_tanh: out[v] = tanh(bias + self + neighbor sum), fp32 out.
__global__ __launch_bounds__(256) void agg_tanh(
    const __hip_bfloat16* __restrict__ M, const int* __restrict__ off,
    const int* __restrict__ csr, const float* __restrict__ bias,
    float* __restrict__ out, int n) {
  int node = (blockIdx.x * 256 + threadIdx.x) >> 6;
  int lane = threadIdx.x & 63;
  if (node >= n) return;
  int f = lane * 2;
  float2 acc = gather_sum((const uint32_t*)M, off, csr, node, lane);
  acc.x = tanhf(acc.x + bias[f]);
  acc.y = tanhf(acc.y + bias[f + 1]);
  *(float2*)(out + (size_t)node * HDIM + f) = acc;
}

// agg2_head: layer-2 aggregation fused with class_prepare + classifier.
__global__ __launch_bounds__(256) void agg2_head(
    const __hip_bfloat16* __restrict__ M, const int* __restrict__ off,
    const int* __restrict__ csr, const float* __restrict__ b2,
    const float* __restrict__ cp_w, const float* __restrict__ cp_b,
    const float* __restrict__ cls_w, const float* __restrict__ cls_b,
    float* __restrict__ out, int n) {
  int node = (blockIdx.x * 256 + threadIdx.x) >> 6;
  int lane = threadIdx.x & 63;
  if (node >= n) return;
  int f = lane * 2;
  float2 acc = gather_sum((const uint32_t*)M, off, csr, node, lane);
  float h0 = tanhf(acc.x + b2[f]);
  float h1 = tanhf(acc.y + b2[f + 1]);
  float4 w = *(const float4*)(cp_w + lane * 4);
  float s0 = h0 * w.x + h1 * w.z;
  float s1 = h0 * w.y + h1 * w.w;
#pragma unroll
  for (int offs = 32; offs; offs >>= 1) {
    s0 += __shfl_xor(s0, offs);
    s1 += __shfl_xor(s1, offs);
  }
  if (lane == 0) {
    float p0 = tanhf(s0 + cp_b[0]);
    float p1 = tanhf(s1 + cp_b[1]);
    float4 o;
    o.x = p0 * cls_w[0] + p1 * cls_w[4] + cls_b[0];
    o.y = p0 * cls_w[1] + p1 * cls_w[5] + cls_b[1];
    o.z = p0 * cls_w[2] + p1 * cls_w[6] + cls_b[2];
    o.w = p0 * cls_w[3] + p1 * cls_w[7] + cls_b[3];
    *(float4*)(out + (size_t)node * 4) = o;
    float* hout = out + (size_t)n * 4;
    *(float2*)(hout + (size_t)node * 2) = make_float2(p0, p1);
  }
}

extern "C" void kernel_launch(void* const* d_in, const int* in_sizes, int n_in,
                              void* d_out, int out_size, void* d_ws, size_t ws_size,
                              hipStream_t stream) {
  const float* x     = (const float*)d_in[0];
  const int*   ei    = (const int*)d_in[1];
  const float* fw    = (const float*)d_in[2];
  const float* fb    = (const float*)d_in[3];
  const float* w1    = (const float*)d_in[4];
  const float* b1    = (const float*)d_in[5];
  const float* w2    = (const float*)d_in[6];
  const float* b2    = (const float*)d_in[7];
  const float* cp_w  = (const float*)d_in[8];
  const float* cp_b  = (const float*)d_in[9];
  const float* cls_w = (const float*)d_in[10];
  const float* cls_b = (const float*)d_in[11];
  float* out = (float*)d_out;

  int n = in_sizes[0] / HDIM;
  int E = in_sizes[1] / 2;
  size_t nh = (size_t)n * HDIM;
  const int WELEM = HDIM * HDIM;

  float* A = (float*)d_ws;                         // H0 -> h1 (fp32)
  __hip_bfloat16* Mb = (__hip_bfloat16*)(A + nh);  // messages (bf16)
  int* deg = (int*)((char*)Mb + nh * sizeof(__hip_bfloat16));
  int* off = deg + n;
  int* cur = off + n + 1;
  int* csr = cur + n;
  int* partials = csr + E;
  ushort* Wsp = (ushort*)(partials + 1024);  // [2][hi|lo][16384]
  ushort* W1h = Wsp;              ushort* W1l = Wsp + WELEM;
  ushort* W2h = Wsp + 2 * WELEM;  ushort* W2l = Wsp + 3 * WELEM;

  int gemmBlocks = (n + BM - 1) / BM;
  int mfmaBlocks = (n + 63) / 64;
  int edgeBlocks = (E + 255) / 256;
  int aggBlocks = (n + 3) / 4;
  int G = (n + 1023) / 1024;

  // layer 0 GEMM (fp32, proven) — fuses deg zeroing; W-split prep for 1&2.
  gemm_tiled<<<gemmBlocks, 256, 0, stream>>>(x, fw, fb, A, n, deg, n);
  prep_w2<<<128, 256, 0, stream>>>(w1, w2, Wsp);

  // CSR build
  hist_dst<<<edgeBlocks, 256, 0, stream>>>(ei, E, n, deg);
  scan1<<<G, 1024, 0, stream>>>(deg, partials, n);
  scan3f<<<G, 1024, 0, stream>>>(deg, partials, off, cur, n);
  fill_csr<<<edgeBlocks, 256, 0, stream>>>(ei, E, n, cur, csr);

  // layer 1: Mb = bf16(A @ w1) via MFMA v3 ; A = tanh(b1 + agg(Mb))
  gemm_mfma2<<<mfmaBlocks, 256, 0, stream>>>(A, W1h, W1l, Mb, n);
  agg_tanh<<<aggBlocks, 256, 0, stream>>>(Mb, off, csr, b1, A, n);
  // layer 2: Mb = bf16(A @ w2) ; fused agg + head
  gemm_mfma2<<<mfmaBlocks, 256, 0, stream>>>(A, W2h, W2l, Mb, n);
  agg2_head<<<aggBlocks, 256, 0, stream>>>(Mb, off, csr, b2, cp_w, cp_b,
                                           cls_w, cls_b, out, n);
}